// Round 9
// baseline (157.258 us; speedup 1.0000x reference)
//
#include <hip/hip_runtime.h>
#include <stdint.h>

// OrthogonalLinear: pyramid Givens circuit, n = m = 512, B = 256.
// T = 1021 layers; layer t has gates (i, i+1) for i = (t&1), (t&1)+2, ...,
// i <= min(t, 1020-t). theta index: k = (t+i)/2 + 1, idx = k(k-1)/2 + (k-1-i).
//
// Table W4 (d_ws), float4 units: pair p (layers t=2p, 2p+1) at [p*256,(p+1)*256).
// Quarter q in 0..3, lane L: idx = p*256 + q*64 + L:
//   q0 = (cE0,sE0,cE1,sE1)   even gates at wires 8L+0, 8L+2
//   q1 = (cE2,sE2,cE3,sE3)   even gates at wires 8L+4, 8L+6
//   q2 = (cO0,sO0,cO1,sO1)   odd  gates at wires 8L+1, 8L+3
//   q3 = (cO2,sO2,cU-1,sU)   odd gate at 8L+5; boundary gate (8L+7) stored
//                            as (c-1, s) so DPP's shifted-in 0 = identity.
// Block p=510 (128 float4, q=0/1, plain (c,s)) = final even layer t=1020.
// Total 130688 float4 = 2.09 MB.
//
// R9: 4 waves/block = 4 rows/block, 64 blocks. Chunks of 6 pairs DMA'd
// global->LDS (double buffer) by all 4 waves cooperatively (6 global_load_lds
// each); consumers ds_read_b128 from LDS. Table bytes transit each CU once
// (DMA, no RF return path); LDS delivers at 256B/cyc shared while VALU runs
// on 4 SIMDs in parallel. Breaks R2-R8's ~135 cyc/pair per-wave VMEM wall.

#define N_WIRES 512
#define BATCH   256
#define PAIRS   510
#define CHUNK   6                      // pairs per chunk; 510 = 6 * 85
#define NCHUNK  85
#define CHUNK4  (CHUNK * 4 * 64)       // 1536 float4 = 24 KB per buffer
#define FINAL4  (PAIRS * 256)          // 130560
#define TOTAL4  (FINAL4 + 128)         // 130688
#define TOTAL2  (TOTAL4 * 2)           // 261376 float2 slots

// ---------------- kernel 1: fused table build ----------------
__global__ __launch_bounds__(256) void fused_kernel(
    const float* __restrict__ thetas, float2* __restrict__ W2) {
  int tid = blockIdx.x * 256 + threadIdx.x;
  if (tid >= TOTAL2) return;
  int p = tid >> 9, r = tid & 511;
  int q = r >> 7, L = (r >> 1) & 63, e = r & 1, h = q >> 1;
  int t = 2 * p + h;
  int i = 8 * L + 4 * (q & 1) + 2 * e + h;
  float c = 1.0f, s = 0.0f;
  if (i <= min(t, 1020 - t)) {
    int k = ((t + i) >> 1) + 1;
    int idx = ((k * (k - 1)) >> 1) + (k - 1 - i);
    __sincosf(thetas[idx], &s, &c);
  }
  if (q == 3 && e == 1) c -= 1.0f;   // boundary gate stored as (c-1, s)
  W2[tid] = make_float2(c, s);
}

// ---------------- kernel 2: apply circuit ----------------
template <int N>
__device__ __forceinline__ void wait_vm() {
  asm volatile("s_waitcnt vmcnt(%0)" ::"i"(N) : "memory");
}

__device__ __forceinline__ float dpp_shr1(float v) {  // lane i <- i-1; lane0 <- 0
  return __int_as_float(
      __builtin_amdgcn_mov_dpp(__float_as_int(v), 0x138, 0xF, 0xF, true));
}
__device__ __forceinline__ float dpp_shl1(float v) {  // lane i <- i+1; lane63 <- 0
  return __int_as_float(
      __builtin_amdgcn_mov_dpp(__float_as_int(v), 0x130, 0xF, 0xF, true));
}

// Packed Givens gate: ab=(a,b), cs=(c,s) -> (c*a+s*b, c*b-s*a), 2 VOP3P instr.
__device__ __forceinline__ float2 gate_pk(float2 cs, float2 ab) {
  float2 t, r;
  asm("v_pk_mul_f32 %0, %1, %2 op_sel:[1,1] op_sel_hi:[1,0] neg_hi:[1,0]"
      : "=v"(t)
      : "v"(cs), "v"(ab));
  asm("v_pk_fma_f32 %0, %1, %2, %3 op_sel:[0,0,0] op_sel_hi:[0,1,1]"
      : "=v"(r)
      : "v"(cs), "v"(ab), "v"(t));
  return r;
}

__device__ __forceinline__ void gate_s(float& a, float& b, float c, float s) {
  float na = fmaf(c, a, s * b);
  float nb = fmaf(c, b, -(s * a));
  a = na;
  b = nb;
}

__device__ __forceinline__ void pair_compute(float2& A, float2& B, float2& C,
                                             float2& D, const float4& q0,
                                             const float4& q1, const float4& q2,
                                             const float4& q3) {
  // even layer: 4 packed gates
  A = gate_pk(make_float2(q0.x, q0.y), A);
  B = gate_pk(make_float2(q0.z, q0.w), B);
  C = gate_pk(make_float2(q1.x, q1.y), C);
  D = gate_pk(make_float2(q1.z, q1.w), D);
  // odd layer
  float cl_m1 = dpp_shr1(q3.z);   // left neighbor's (c-1); lane0 -> 0 = identity
  float sl    = dpp_shr1(q3.w);   // lane0 -> 0
  float rv0 = dpp_shl1(A.x);      // right neighbor's wire 8L+8 (post-even)
  float lv7 = dpp_shr1(D.y);      // left neighbor's wire 8L-1 (post-even)
  gate_s(A.y, B.x, q2.x, q2.y);
  gate_s(B.y, C.x, q2.z, q2.w);
  gate_s(C.y, D.x, q3.x, q3.y);
  // boundary: up-gate (8L+7, 8L+8) a-side, c = 1 + q3.z:
  float nv7 = fmaf(q3.w, rv0, fmaf(q3.z, D.y, D.y));
  // down-gate (8L-1, 8L) b-side, c = 1 + cl_m1:
  float nv0 = fmaf(-sl, lv7, fmaf(cl_m1, A.x, A.x));
  D.y = nv7;
  A.x = nv0;
}

// Issue this wave's 6 of the chunk's 24 DMA loads (1 KB each).
__device__ __forceinline__ void issue_chunk(const float4* __restrict__ Wg,
                                            float4* smem, int c, int bsel,
                                            int wave, int lane) {
  const float4* src = Wg + c * (CHUNK * 256) + wave * (6 * 64) + lane;
  float4* dst = smem + bsel * CHUNK4 + wave * (6 * 64);  // wave-uniform base
#pragma unroll
  for (int j = 0; j < 6; ++j) {
    __builtin_amdgcn_global_load_lds(
        (__attribute__((address_space(1))) uint32_t*)(src + j * 64),
        (__attribute__((address_space(3))) uint32_t*)(dst + j * 64),
        16, 0, 0);
  }
}

__global__ __launch_bounds__(256, 1) void circuit_kernel(
    const float* __restrict__ x, const float* __restrict__ W,
    const float* __restrict__ bias, float* __restrict__ out) {
  __shared__ float4 smem[2 * CHUNK4];   // 49152 B
  const int lane = threadIdx.x & 63;
  const int wave = threadIdx.x >> 6;
  const int row = blockIdx.x * 4 + wave;   // each wave owns one row
  const float4* __restrict__ Wg = (const float4*)W;

  const float* xr = x + row * N_WIRES + lane * 8;
  float4 x0 = *(const float4*)(xr);
  float4 x1 = *(const float4*)(xr + 4);
  float2 A = make_float2(x0.x, x0.y), B = make_float2(x0.z, x0.w);
  float2 C = make_float2(x1.x, x1.y), D = make_float2(x1.z, x1.w);

  // prologue: chunk 0 into buffer 0
  issue_chunk(Wg, smem, 0, 0, wave, lane);
  wait_vm<0>();
  __syncthreads();

  for (int k = 0; k < NCHUNK; ++k) {
    if (k + 1 < NCHUNK) issue_chunk(Wg, smem, k + 1, (k + 1) & 1, wave, lane);
    const float4* buf = smem + (k & 1) * CHUNK4;
#pragma unroll
    for (int pr = 0; pr < CHUNK; ++pr) {
      float4 q0 = buf[(pr * 4 + 0) * 64 + lane];
      float4 q1 = buf[(pr * 4 + 1) * 64 + lane];
      float4 q2 = buf[(pr * 4 + 2) * 64 + lane];
      float4 q3 = buf[(pr * 4 + 3) * 64 + lane];
      pair_compute(A, B, C, D, q0, q1, q2, q3);
    }
    // own 6 DMA loads for chunk k+1 were issued ~6 pairs (~700 cyc) ago.
    wait_vm<0>();
    __syncthreads();
  }

  // Final even layer t = 1020 (block p=510, q0/q1, plain (c,s), pre-masked).
  float4 f0 = Wg[FINAL4 + lane];
  float4 f1 = Wg[FINAL4 + 64 + lane];
  A = gate_pk(make_float2(f0.x, f0.y), A);
  B = gate_pk(make_float2(f0.z, f0.w), B);
  C = gate_pk(make_float2(f1.x, f1.y), C);
  D = gate_pk(make_float2(f1.z, f1.w), D);

  const float* br = bias + lane * 8;
  float4 b0 = *(const float4*)(br);
  float4 b1 = *(const float4*)(br + 4);
  float* orow = out + row * N_WIRES + lane * 8;
  float4 o0 = {A.x + b0.x, A.y + b0.y, B.x + b0.z, B.y + b0.w};
  float4 o1 = {C.x + b1.x, C.y + b1.y, D.x + b1.z, D.y + b1.w};
  *(float4*)(orow) = o0;
  *(float4*)(orow + 4) = o1;
}

extern "C" void kernel_launch(void* const* d_in, const int* in_sizes, int n_in,
                              void* d_out, int out_size, void* d_ws,
                              size_t ws_size, hipStream_t stream) {
  const float* x = (const float*)d_in[0];       // (256, 512) f32
  const float* thetas = (const float*)d_in[1];  // (130816,) f32
  const float* bias = (const float*)d_in[2];    // (512,) f32
  float* out = (float*)d_out;                   // (256, 512) f32

  float* W = (float*)d_ws;                      // 130688 float4 = 2,091,008 B

  fused_kernel<<<(TOTAL2 + 255) / 256, 256, 0, stream>>>(thetas, (float2*)W);
  circuit_kernel<<<BATCH / 4, 256, 0, stream>>>(x, W, bias, out);
}

// Round 10
// 110.215 us; speedup vs baseline: 1.4268x; 1.4268x over previous
//
#include <hip/hip_runtime.h>
#include <hip/hip_fp16.h>
#include <stdint.h>

// OrthogonalLinear: pyramid Givens circuit, n = m = 512, B = 256.
// T = 1021 layers; layer t has gates (i, i+1) for i = (t&1), (t&1)+2, ...,
// i <= min(t, 1020-t). theta index: k = (t+i)/2 + 1, idx = k(k-1)/2 + (k-1-i).
//
// R10: f16 table. Each gate = one dword = half2(c, s). Pair p (layers t=2p,
// t=2p+1) occupies 128 uint4 (2 KB): uint4 idx = p*128 + h*64 + L, where
// h=0 -> even-layer gates of lane L: dwords (x,y,z,w) = gates at wires
// 8L+0, 8L+2, 8L+4, 8L+6; h=1 -> odd-layer gates at wires 8L+1, 8L+3, 8L+5,
// and w = BOUNDARY gate (8L+7, 8L+8) stored as half2(c-1, s) so the DPP
// shifted-in 0 dword decodes to identity (kills the lane-0 cndmask).
// Final even layer t=1020 at uint4 [FINAL4, FINAL4+64): lane L, 4 even gates,
// plain (c,s). Total 65344 uint4 = 1.02 MB. Dead slots = identity.
//
// circuit: R7's proven wave-per-row register ring (PF=10 pairs = 2 loads/pair,
// 20 outstanding, per-pair asm vmcnt(18) barrier), DPP cross-lane, packed-f32
// gate math; c/s converted per-gate via v_cvt from half2. Halves the
// per-wave cache-line count (the measured ~140 cyc/pair mem wall of R2-R9).

#define N_WIRES 512
#define BATCH   256
#define PAIRS   510
#define PF      10                  // ring depth; 510 = 10 * 51
#define FINAL4  (PAIRS * 128)       // 65280 uint4
#define TOTAL4  (FINAL4 + 64)       // 65344 uint4
#define TOTALH2 (TOTAL4 * 4)        // 261376 half2 slots

// ---------------- kernel 1: fused f16 table build ----------------
__global__ __launch_bounds__(256) void fused_kernel(
    const float* __restrict__ thetas, __half2* __restrict__ Wh) {
  int tid = blockIdx.x * 256 + threadIdx.x;
  if (tid >= TOTALH2) return;
  float c = 1.0f, s = 0.0f;
  if (tid < PAIRS * 512) {
    int p = tid >> 9, r = tid & 511;
    int h = r >> 8, rr = r & 255, L = rr >> 2, j = rr & 3;
    int t = 2 * p + h;
    int i = 8 * L + 2 * j + h;
    if (i <= min(t, 1020 - t)) {
      int k = ((t + i) >> 1) + 1;
      int idx = ((k * (k - 1)) >> 1) + (k - 1 - i);
      __sincosf(thetas[idx], &s, &c);
    }
    if (h == 1 && j == 3) c -= 1.0f;   // boundary gate stored as (c-1, s)
  } else {
    int e = tid - PAIRS * 512;         // final even layer t = 1020
    int L = e >> 2, j = e & 3;
    if (8 * L + 2 * j == 0) __sincosf(thetas[130815], &s, &c);
  }
  Wh[tid] = __floats2half2_rn(c, s);
}

// ---------------- kernel 2: apply circuit, wave per row ----------------
template <int N>
__device__ __forceinline__ void wait_vm() {
  asm volatile("s_waitcnt vmcnt(%0)" ::"i"(N) : "memory");
}

__device__ __forceinline__ float dpp_shr1(float v) {  // lane i <- i-1; lane0 <- 0
  return __int_as_float(
      __builtin_amdgcn_mov_dpp(__float_as_int(v), 0x138, 0xF, 0xF, true));
}
__device__ __forceinline__ float dpp_shl1(float v) {  // lane i <- i+1; lane63 <- 0
  return __int_as_float(
      __builtin_amdgcn_mov_dpp(__float_as_int(v), 0x130, 0xF, 0xF, true));
}
__device__ __forceinline__ uint32_t dpp_shr1_u(uint32_t v) {
  return (uint32_t)__builtin_amdgcn_mov_dpp((int)v, 0x138, 0xF, 0xF, true);
}

__device__ __forceinline__ float2 h2f(uint32_t u) {  // half2(c,s) -> float2
  return __half22float2(__builtin_bit_cast(__half2, u));
}

// Packed Givens gate: ab=(a,b), cs=(c,s) -> (c*a+s*b, c*b-s*a), 2 VOP3P instr.
__device__ __forceinline__ float2 gate_pk(float2 cs, float2 ab) {
  float2 t, r;
  asm("v_pk_mul_f32 %0, %1, %2 op_sel:[1,1] op_sel_hi:[1,0] neg_hi:[1,0]"
      : "=v"(t)
      : "v"(cs), "v"(ab));
  asm("v_pk_fma_f32 %0, %1, %2, %3 op_sel:[0,0,0] op_sel_hi:[0,1,1]"
      : "=v"(r)
      : "v"(cs), "v"(ab), "v"(t));
  return r;
}

__device__ __forceinline__ void gate_s(float& a, float& b, float c, float s) {
  float na = fmaf(c, a, s * b);
  float nb = fmaf(c, b, -(s * a));
  a = na;
  b = nb;
}

__device__ __forceinline__ void pair_compute(float2& A, float2& B, float2& C,
                                             float2& D, const uint4& E,
                                             const uint4& O) {
  // even layer: 4 packed gates (cvt from half2 feeds pk math directly)
  A = gate_pk(h2f(E.x), A);
  B = gate_pk(h2f(E.y), B);
  C = gate_pk(h2f(E.z), C);
  D = gate_pk(h2f(E.w), D);
  // odd layer: boundary gate dword DPP'd as a unit (lane0 gets 0 = identity)
  uint32_t bl = dpp_shr1_u(O.w);
  float rv0 = dpp_shl1(A.x);      // right neighbor's wire 8L+8 (post-even)
  float lv7 = dpp_shr1(D.y);      // left neighbor's wire 8L-1 (post-even)
  float2 gl = h2f(bl);            // left boundary (c-1, s); lane0 -> (0,0)
  float2 gu = h2f(O.w);           // own boundary (c-1, s)
  float2 g4 = h2f(O.x), g5 = h2f(O.y), g6 = h2f(O.z);
  gate_s(A.y, B.x, g4.x, g4.y);
  gate_s(B.y, C.x, g5.x, g5.y);
  gate_s(C.y, D.x, g6.x, g6.y);
  // up-gate (8L+7, 8L+8) a-side, c = 1 + gu.x:
  float nv7 = fmaf(gu.y, rv0, fmaf(gu.x, D.y, D.y));
  // down-gate (8L-1, 8L) b-side, c = 1 + gl.x:
  float nv0 = fmaf(-gl.y, lv7, fmaf(gl.x, A.x, A.x));
  D.y = nv7;
  A.x = nv0;
}

__global__ __launch_bounds__(64, 1) void circuit_kernel(
    const float* __restrict__ x, const uint32_t* __restrict__ W,
    const float* __restrict__ bias, float* __restrict__ out) {
  const int lane = threadIdx.x;
  const int row = blockIdx.x;
  const uint4* __restrict__ Wg = (const uint4*)W;

  // Register ring: PF pairs x 2 uint4 = 80 VGPRs. Pointer induction.
  uint4 R[PF][2];
  const uint4* pw = Wg + lane;
#pragma unroll
  for (int s = 0; s < PF; ++s) {
    R[s][0] = pw[0];     // even-layer quad
    R[s][1] = pw[64];    // odd-layer quad
    pw += 128;
  }

  const float* xr = x + row * N_WIRES + lane * 8;
  float4 x0 = *(const float4*)(xr);
  float4 x1 = *(const float4*)(xr + 4);
  float2 A = make_float2(x0.x, x0.y), B = make_float2(x0.z, x0.w);
  float2 C = make_float2(x1.x, x1.y), D = make_float2(x1.z, x1.w);

  for (int blk = 0; blk < (PAIRS / PF) - 1; ++blk) {   // 50 iterations
#pragma unroll
    for (int s = 0; s < PF; ++s) {
      // outstanding = 20 table loads; retire exactly the oldest pair's 2.
      wait_vm<18>();
      pair_compute(A, B, C, D, R[s][0], R[s][1]);
      R[s][0] = pw[0];
      R[s][1] = pw[64];
      pw += 128;
    }
  }

  // Drain: pairs 500..509 already in ring; one full wait.
  wait_vm<0>();
#pragma unroll
  for (int s = 0; s < PF; ++s) pair_compute(A, B, C, D, R[s][0], R[s][1]);

  // Final even layer t = 1020 (plain (c,s), pre-masked identity).
  uint4 F = Wg[FINAL4 + lane];
  A = gate_pk(h2f(F.x), A);
  B = gate_pk(h2f(F.y), B);
  C = gate_pk(h2f(F.z), C);
  D = gate_pk(h2f(F.w), D);

  const float* br = bias + lane * 8;
  float4 b0 = *(const float4*)(br);
  float4 b1 = *(const float4*)(br + 4);
  float* orow = out + row * N_WIRES + lane * 8;
  float4 o0 = {A.x + b0.x, A.y + b0.y, B.x + b0.z, B.y + b0.w};
  float4 o1 = {C.x + b1.x, C.y + b1.y, D.x + b1.z, D.y + b1.w};
  *(float4*)(orow) = o0;
  *(float4*)(orow + 4) = o1;
}

extern "C" void kernel_launch(void* const* d_in, const int* in_sizes, int n_in,
                              void* d_out, int out_size, void* d_ws,
                              size_t ws_size, hipStream_t stream) {
  const float* x = (const float*)d_in[0];       // (256, 512) f32
  const float* thetas = (const float*)d_in[1];  // (130816,) f32
  const float* bias = (const float*)d_in[2];    // (512,) f32
  float* out = (float*)d_out;                   // (256, 512) f32

  uint32_t* W = (uint32_t*)d_ws;                // 65344 uint4 = 1,045,504 B

  fused_kernel<<<(TOTALH2 + 255) / 256, 256, 0, stream>>>(thetas, (__half2*)W);
  circuit_kernel<<<BATCH, 64, 0, stream>>>(x, W, bias, out);
}